// Round 4
// baseline (451.209 us; speedup 1.0000x reference)
//
#include <hip/hip_runtime.h>
#include <cstdint>
#include <cstddef>

#define NAG 32
#define N1C 32
#define N2C 496
#define NF 528
#define HD 64
#define SD 512

typedef __attribute__((ext_vector_type(8))) short bf16x8;
typedef __attribute__((ext_vector_type(4))) float f32x4;
#define MFMA16(a, b, c) __builtin_amdgcn_mfma_f32_16x16x32_bf16(a, b, c, 0, 0, 0)

__device__ __forceinline__ unsigned short f2bf(float f) {
    unsigned int u = __float_as_uint(f);
    u += 0x7fffu + ((u >> 16) & 1u);
    return (unsigned short)(u >> 16);
}
__device__ __forceinline__ unsigned int pack2(float a, float b) {
    return (unsigned int)f2bf(a) | ((unsigned int)f2bf(b) << 16);
}
__device__ __forceinline__ float elu_f(float x) {
    return x > 0.f ? x : (__expf(x) - 1.f);
}

// ---- d_ws layout (ushort/bf16): wsT[64][512], wb1T[64][512], wzT[64][512],
//      wa1T[64][128], wa2T[528][64]
#define OFF_WST   0
#define OFF_WB1T  32768
#define OFF_WZT   65536
#define OFF_WA1T  98304
#define OFF_WA2T  106496
#define PREP_TOT  140288

// ---------------- Kernel 0: weight transpose + bf16 convert ----------------
__global__ __launch_bounds__(256) void prep_kernel(
    const float* __restrict__ ws_w, const float* __restrict__ wb1_w,
    const float* __restrict__ wz_w, const float* __restrict__ wa1_w,
    const float* __restrict__ wa2_w, unsigned short* __restrict__ ws)
{
    int i = blockIdx.x * 256 + threadIdx.x;
    if (i >= PREP_TOT) return;
    float v;
    if (i < OFF_WB1T) {
        int j = i - OFF_WST; int n = j >> 9, k = j & 511;
        v = ws_w[k * 64 + n];
    } else if (i < OFF_WZT) {
        int j = i - OFF_WB1T; int n = j >> 9, k = j & 511;
        v = wb1_w[k * 64 + n];
    } else if (i < OFF_WA1T) {
        int j = i - OFF_WZT; int n = j >> 9, k = j & 511;
        v = wz_w[k * 64 + n];
    } else if (i < OFF_WA2T) {
        int j = i - OFF_WA1T; int n = j >> 7, k = j & 127;
        v = wa1_w[k * 64 + n];
    } else {
        int j = i - OFF_WA2T; int n = j >> 6, k = j & 63;
        v = wa2_w[k * NF + n];
    }
    ws[i] = f2bf(v);
}

// ---------------- Kernel 1: shape functions (unchanged) ----------------
#define SROWS 64
__global__ __launch_bounds__(576) void shape_kernel(
    const float* __restrict__ q,
    const float* __restrict__ w1_1, const float* __restrict__ b1_1,
    const float* __restrict__ w2_1, const float* __restrict__ b2_1,
    const float* __restrict__ w3_1, const float* __restrict__ b3_1,
    const float* __restrict__ w1_2, const float* __restrict__ b1_2,
    const float* __restrict__ w2_2, const float* __restrict__ b2_2,
    const float* __restrict__ w3_2, const float* __restrict__ b3_2,
    float* __restrict__ shape_out, int B)
{
    __shared__ float qs[SROWS][NAG];

    int tid = threadIdx.x;
    int f = tid;
    bool valid = f < NF;
    int fe = valid ? f : (NF - 1);

    float w1a[8], w1b[8], b1v[8], w2v[32], b2v[4], w3v[4], b3v;
    int pi, pj;
    if (fe < N1C) {
        int n = fe;
        pi = n; pj = n;
        #pragma unroll
        for (int k = 0; k < 8; k++) { w1a[k] = fabsf(w1_1[n*8+k]); w1b[k] = 0.f; b1v[k] = b1_1[n*8+k]; }
        #pragma unroll
        for (int t = 0; t < 32; t++) w2v[t] = fabsf(w2_1[n*32+t]);
        #pragma unroll
        for (int j = 0; j < 4; j++) { b2v[j] = b2_1[n*4+j]; w3v[j] = fabsf(w3_1[n*4+j]); }
        b3v = b3_1[n];
    } else {
        int n = fe - N1C;
        int p = n, i = 0, c = NAG - 1;
        while (p >= c) { p -= c; c--; i++; }
        pi = i; pj = i + 1 + p;
        #pragma unroll
        for (int k = 0; k < 8; k++) { w1a[k] = fabsf(w1_2[n*16+k]); w1b[k] = fabsf(w1_2[n*16+8+k]); b1v[k] = b1_2[n*8+k]; }
        #pragma unroll
        for (int t = 0; t < 32; t++) w2v[t] = fabsf(w2_2[n*32+t]);
        #pragma unroll
        for (int j = 0; j < 4; j++) { b2v[j] = b2_2[n*4+j]; w3v[j] = fabsf(w3_2[n*4+j]); }
        b3v = b3_2[n];
    }

    int row0 = blockIdx.x * SROWS;
    if (tid < 512) {
        float4 v = *(const float4*)&q[(size_t)row0 * NAG + tid * 4];
        *(float4*)&((float*)qs)[tid * 4] = v;
    }
    __syncthreads();

    #pragma unroll 4
    for (int rr = 0; rr < SROWS; rr++) {
        float qi = qs[rr][pi];
        float qj = qs[rr][pj];
        float h1[8];
        #pragma unroll
        for (int k = 0; k < 8; k++) h1[k] = elu_f(w1a[k]*qi + w1b[k]*qj + b1v[k]);
        float h2[4];
        #pragma unroll
        for (int j = 0; j < 4; j++) {
            float a = b2v[j];
            #pragma unroll
            for (int k = 0; k < 8; k++) a += h1[k] * w2v[k*4 + j];
            h2[j] = elu_f(a);
        }
        float fv = b3v;
        #pragma unroll
        for (int j = 0; j < 4; j++) fv += h2[j] * w3v[j];
        if (valid) shape_out[(size_t)(row0 + rr) * NF + f] = fv;
    }
}

// ---------------- Kernel 2: cooperative 16-row MFMA encoder ----------------
// Occupancy was grid-limited (2048 waves total = 2 waves/SIMD). Now a
// 256-thread block handles only 16 rows; the 4 waves SPLIT the 12 K-loop
// output tiles (3 each, full K=512 -> no cross-wave reduction), the 4 wa1
// tiles (1 each), and the 33 wa2 tiles (strided, LDS softmax reduce).
// Grid = B/16 = 2048 blocks -> up to 8 blocks/CU (LDS ~7.3KB, VGPR<=84).
#define RB 16

// tile T in 0..11: group G=T>>2 (0=ws->sComb[0:64), 1=wb1->bias, 2=wz->sComb[64:128));
// ct = T&3 (output 16-col tile within the 64-col GEMM).
template<int T>
__device__ __forceinline__ void tile_epi(const f32x4& acc,
    const float* __restrict__ ws_b, const float* __restrict__ wz_b,
    const float* __restrict__ wb1_b, const float* __restrict__ wb2_w,
    int col, int quad, unsigned short (*sComb)[136], float* pbias)
{
    constexpr int G = T >> 2, C = T & 3;
    if constexpr (G == 0) {
        float b = ws_b[C*16 + col];
        #pragma unroll
        for (int r = 0; r < 4; r++)
            sComb[quad*4 + r][C*16 + col] = f2bf(fmaxf(acc[r] + b, 0.f));
    } else if constexpr (G == 2) {
        float b = wz_b[C*16 + col];
        #pragma unroll
        for (int r = 0; r < 4; r++)
            sComb[quad*4 + r][64 + C*16 + col] = f2bf(fmaxf(acc[r] + b, 0.f));
    } else {
        float b = wb1_b[C*16 + col], w2 = wb2_w[C*16 + col];
        #pragma unroll
        for (int r = 0; r < 4; r++)
            pbias[r] += fmaxf(acc[r] + b, 0.f) * w2;
    }
}

template<int W>
__device__ __forceinline__ void phase1(
    const float* __restrict__ srowS, const float* __restrict__ srowZ,
    const unsigned short* __restrict__ wsbuf,
    const float* __restrict__ ws_b, const float* __restrict__ wz_b,
    const float* __restrict__ wb1_b, const float* __restrict__ wb2_w,
    int col, int quad,
    unsigned short (*sComb)[136], float (*sBias)[16])
{
    constexpr int T0 = W*3, T1 = W*3 + 1, T2 = W*3 + 2;
    constexpr bool needS = (T0 < 8);   // any tile in groups 0/1 uses state-A
    constexpr bool needZ = (T2 >= 8);  // any tile in group 2 uses sem-A

    constexpr int G0 = T0 >> 2, C0 = T0 & 3;
    constexpr int G1 = T1 >> 2, C1 = T1 & 3;
    constexpr int G2 = T2 >> 2, C2 = T2 & 3;
    const unsigned short* bp0 = wsbuf + (G0==0?OFF_WST:G0==1?OFF_WB1T:OFF_WZT) + (C0*16 + col)*SD + quad*8;
    const unsigned short* bp1 = wsbuf + (G1==0?OFF_WST:G1==1?OFF_WB1T:OFF_WZT) + (C1*16 + col)*SD + quad*8;
    const unsigned short* bp2 = wsbuf + (G2==0?OFF_WST:G2==1?OFF_WB1T:OFF_WZT) + (C2*16 + col)*SD + quad*8;

    f32x4 a0 = {0.f,0.f,0.f,0.f};
    f32x4 a1 = {0.f,0.f,0.f,0.f};
    f32x4 a2 = {0.f,0.f,0.f,0.f};

    #pragma unroll 2
    for (int ks = 0; ks < 16; ks++) {
        bf16x8 as = {}, az = {};
        if constexpr (needS) {
            float4 s0 = *(const float4*)(srowS + ks*32);
            float4 s1 = *(const float4*)(srowS + ks*32 + 4);
            unsigned int* p = (unsigned int*)&as;
            p[0] = pack2(s0.x, s0.y); p[1] = pack2(s0.z, s0.w);
            p[2] = pack2(s1.x, s1.y); p[3] = pack2(s1.z, s1.w);
        }
        if constexpr (needZ) {
            float4 z0 = *(const float4*)(srowZ + ks*32);
            float4 z1 = *(const float4*)(srowZ + ks*32 + 4);
            unsigned int* p = (unsigned int*)&az;
            p[0] = pack2(z0.x, z0.y); p[1] = pack2(z0.z, z0.w);
            p[2] = pack2(z1.x, z1.y); p[3] = pack2(z1.z, z1.w);
        }
        int wof = ks * 32;
        a0 = MFMA16((T0 >= 8) ? az : as, *(const bf16x8*)(bp0 + wof), a0);
        a1 = MFMA16((T1 >= 8) ? az : as, *(const bf16x8*)(bp1 + wof), a1);
        a2 = MFMA16((T2 >= 8) ? az : as, *(const bf16x8*)(bp2 + wof), a2);
    }

    float pbias[4] = {0.f, 0.f, 0.f, 0.f};
    tile_epi<T0>(a0, ws_b, wz_b, wb1_b, wb2_w, col, quad, sComb, pbias);
    tile_epi<T1>(a1, ws_b, wz_b, wb1_b, wb2_w, col, quad, sComb, pbias);
    tile_epi<T2>(a2, ws_b, wz_b, wb1_b, wb2_w, col, quad, sComb, pbias);

    if constexpr (W == 1 || W == 2) {
        #pragma unroll
        for (int r = 0; r < 4; r++) {
            float p = pbias[r];
            #pragma unroll
            for (int m = 1; m < 16; m <<= 1) p += __shfl_xor(p, m, 64);
            if (col == 0) sBias[W - 1][quad*4 + r] = p;
        }
    }
}

__global__ __launch_bounds__(256, 6) void enc_mfma(
    const float* __restrict__ state,
    const float* __restrict__ sem,
    const unsigned short* __restrict__ wsbuf,
    const float* __restrict__ ws_b, const float* __restrict__ wz_b,
    const float* __restrict__ wa1_b, const float* __restrict__ wa2_b,
    const float* __restrict__ wb1_b, const float* __restrict__ wb2_w,
    const float* __restrict__ wb2_b,
    const float* __restrict__ shape_out,
    float* __restrict__ q_total,
    float* __restrict__ attn_out)
{
    __shared__ unsigned short sComb[RB][136]; // [relu(C1)|relu(C3)], padded
    __shared__ unsigned short sH[RB][72];     // relu(C4), padded
    __shared__ float sBias[2][RB];            // bias-head partials (waves 1,2)
    __shared__ float sRedS[4][RB];            // softmax denom partials per wave
    __shared__ float sRedW[4][RB];            // weighted-sum partials per wave

    const unsigned short* wa1T = wsbuf + OFF_WA1T;
    const unsigned short* wa2T = wsbuf + OFF_WA2T;

    int tid  = threadIdx.x;
    int lane = tid & 63;
    int w    = tid >> 6;
    int col  = lane & 15;
    int quad = lane >> 4;
    int r0   = blockIdx.x * RB;

    const float* srowS = state + (size_t)(r0 + col) * SD + quad * 8;
    const float* srowZ = sem   + (size_t)(r0 + col) * SD + quad * 8;

    // ---- phase 1: 12 output tiles (3 GEMMs x 4 ct) split 3-per-wave ----
    switch (w) {
        case 0:  phase1<0>(srowS, srowZ, wsbuf, ws_b, wz_b, wb1_b, wb2_w, col, quad, sComb, sBias); break;
        case 1:  phase1<1>(srowS, srowZ, wsbuf, ws_b, wz_b, wb1_b, wb2_w, col, quad, sComb, sBias); break;
        case 2:  phase1<2>(srowS, srowZ, wsbuf, ws_b, wz_b, wb1_b, wb2_w, col, quad, sComb, sBias); break;
        default: phase1<3>(srowS, srowZ, wsbuf, ws_b, wz_b, wb1_b, wb2_w, col, quad, sComb, sBias); break;
    }
    __syncthreads();

    // ---- C4 = comb @ wa1 : wave w owns output cols [16w,16w+16) ----
    f32x4 accH = {0.f,0.f,0.f,0.f};
    #pragma unroll
    for (int ks = 0; ks < 4; ks++) {
        bf16x8 a = *(const bf16x8*)&sComb[col][ks*32 + quad*8];
        bf16x8 b = *(const bf16x8*)&wa1T[(w*16 + col)*128 + ks*32 + quad*8];
        accH = MFMA16(a, b, accH);
    }
    {
        float bh = wa1_b[w*16 + col];
        #pragma unroll
        for (int r = 0; r < 4; r++)
            sH[quad*4 + r][w*16 + col] = f2bf(fmaxf(accH[r] + bh, 0.f));
    }
    __syncthreads();

    bf16x8 ha0 = *(const bf16x8*)&sH[col][quad*8];
    bf16x8 ha1 = *(const bf16x8*)&sH[col][32 + quad*8];

    // ---- pass 1: partial softmax denom + weighted sum over this wave's nt ----
    float sAcc[4] = {0.f,0.f,0.f,0.f};
    float wAcc[4] = {0.f,0.f,0.f,0.f};
    for (int nt = w; nt < 33; nt += 4) {
        f32x4 acc = {0.f,0.f,0.f,0.f};
        const unsigned short* wp = &wa2T[(nt*16 + col)*64 + quad*8];
        acc = MFMA16(ha0, *(const bf16x8*)wp, acc);
        acc = MFMA16(ha1, *(const bf16x8*)(wp + 32), acc);
        float lb = wa2_b[nt*16 + col];
        #pragma unroll
        for (int r = 0; r < 4; r++) {
            float e = __expf(acc[r] + lb);
            sAcc[r] += e;
            wAcc[r] += e * shape_out[(size_t)(r0 + quad*4 + r) * NF + nt*16 + col];
        }
    }
    #pragma unroll
    for (int r = 0; r < 4; r++) {
        float s = sAcc[r], ww = wAcc[r];
        #pragma unroll
        for (int m = 1; m < 16; m <<= 1) { s += __shfl_xor(s, m, 64); ww += __shfl_xor(ww, m, 64); }
        if (col == 0) { sRedS[w][quad*4 + r] = s; sRedW[w][quad*4 + r] = ww; }
    }
    __syncthreads();

    float inv[4];
    #pragma unroll
    for (int r = 0; r < 4; r++) {
        int row = quad*4 + r;
        float st = sRedS[0][row] + sRedS[1][row] + sRedS[2][row] + sRedS[3][row];
        inv[r] = 1.f / st;
        if (w == 0 && col == 0) {
            float wt = sRedW[0][row] + sRedW[1][row] + sRedW[2][row] + sRedW[3][row];
            q_total[r0 + row] = wt * inv[r] + sBias[0][row] + sBias[1][row] + wb2_b[0];
        }
    }

    // ---- pass 2: recompute this wave's logits, write normalized attention ----
    for (int nt = w; nt < 33; nt += 4) {
        f32x4 acc = {0.f,0.f,0.f,0.f};
        const unsigned short* wp = &wa2T[(nt*16 + col)*64 + quad*8];
        acc = MFMA16(ha0, *(const bf16x8*)wp, acc);
        acc = MFMA16(ha1, *(const bf16x8*)(wp + 32), acc);
        float lb = wa2_b[nt*16 + col];
        #pragma unroll
        for (int r = 0; r < 4; r++) {
            float e = __expf(acc[r] + lb);
            attn_out[(size_t)(r0 + quad*4 + r) * NF + nt*16 + col] = e * inv[r];
        }
    }
}

extern "C" void kernel_launch(void* const* d_in, const int* in_sizes, int n_in,
                              void* d_out, int out_size, void* d_ws, size_t ws_size,
                              hipStream_t stream) {
    const float* q     = (const float*)d_in[0];
    const float* state = (const float*)d_in[1];
    const float* sem   = (const float*)d_in[2];
    const float* w1_1  = (const float*)d_in[3];
    const float* b1_1  = (const float*)d_in[4];
    const float* w2_1  = (const float*)d_in[5];
    const float* b2_1  = (const float*)d_in[6];
    const float* w3_1  = (const float*)d_in[7];
    const float* b3_1  = (const float*)d_in[8];
    const float* w1_2  = (const float*)d_in[9];
    const float* b1_2  = (const float*)d_in[10];
    const float* w2_2  = (const float*)d_in[11];
    const float* b2_2  = (const float*)d_in[12];
    const float* w3_2  = (const float*)d_in[13];
    const float* b3_2  = (const float*)d_in[14];
    const float* ws_w  = (const float*)d_in[15];
    const float* ws_b  = (const float*)d_in[16];
    const float* wz_w  = (const float*)d_in[17];
    const float* wz_b  = (const float*)d_in[18];
    const float* wa1_w = (const float*)d_in[19];
    const float* wa1_b = (const float*)d_in[20];
    const float* wa2_w = (const float*)d_in[21];
    const float* wa2_b = (const float*)d_in[22];
    const float* wb1_w = (const float*)d_in[23];
    const float* wb1_b = (const float*)d_in[24];
    const float* wb2_w = (const float*)d_in[25];
    const float* wb2_b = (const float*)d_in[26];

    int B = in_sizes[0] / NAG;

    float* out_q    = (float*)d_out;                 // [B]
    float* out_attn = out_q + B;                     // [B, NF]
    float* out_shp  = out_attn + (size_t)B * NF;     // [B, NF]

    unsigned short* wsbuf = (unsigned short*)d_ws;

    prep_kernel<<<(PREP_TOT + 255) / 256, 256, 0, stream>>>(
        ws_w, wb1_w, wz_w, wa1_w, wa2_w, wsbuf);

    shape_kernel<<<B / SROWS, 576, 0, stream>>>(q,
        w1_1, b1_1, w2_1, b2_1, w3_1, b3_1,
        w1_2, b1_2, w2_2, b2_2, w3_2, b3_2,
        out_shp, B);

    enc_mfma<<<B / RB, 256, 0, stream>>>(state, sem, wsbuf,
        ws_b, wz_b, wa1_b, wa2_b, wb1_b, wb2_w, wb2_b,
        out_shp, out_q, out_attn);
}

// Round 5
// 405.317 us; speedup vs baseline: 1.1132x; 1.1132x over previous
//
#include <hip/hip_runtime.h>
#include <cstdint>
#include <cstddef>

#define NAG 32
#define N1C 32
#define N2C 496
#define NF 528
#define HD 64
#define SD 512

typedef __attribute__((ext_vector_type(8))) short bf16x8;
typedef __attribute__((ext_vector_type(4))) float f32x4;
#define MFMA16(a, b, c) __builtin_amdgcn_mfma_f32_16x16x32_bf16(a, b, c, 0, 0, 0)

__device__ __forceinline__ unsigned short f2bf(float f) {
    unsigned int u = __float_as_uint(f);
    u += 0x7fffu + ((u >> 16) & 1u);
    return (unsigned short)(u >> 16);
}
__device__ __forceinline__ unsigned int pack2(float a, float b) {
    return (unsigned int)f2bf(a) | ((unsigned int)f2bf(b) << 16);
}
__device__ __forceinline__ float elu_f(float x) {
    return x > 0.f ? x : (__expf(x) - 1.f);
}

// ---- d_ws layout (ushort/bf16): wsT[64][512], wb1T[64][512], wzT[64][512],
//      wa1T[64][128], wa2T[528][64]
#define OFF_WST   0
#define OFF_WB1T  32768
#define OFF_WZT   65536
#define OFF_WA1T  98304
#define OFF_WA2T  106496
#define PREP_TOT  140288

// ---------------- Kernel 0: weight transpose + bf16 convert ----------------
__global__ __launch_bounds__(256) void prep_kernel(
    const float* __restrict__ ws_w, const float* __restrict__ wb1_w,
    const float* __restrict__ wz_w, const float* __restrict__ wa1_w,
    const float* __restrict__ wa2_w, unsigned short* __restrict__ ws)
{
    int i = blockIdx.x * 256 + threadIdx.x;
    if (i >= PREP_TOT) return;
    float v;
    if (i < OFF_WB1T) {
        int j = i - OFF_WST; int n = j >> 9, k = j & 511;
        v = ws_w[k * 64 + n];
    } else if (i < OFF_WZT) {
        int j = i - OFF_WB1T; int n = j >> 9, k = j & 511;
        v = wb1_w[k * 64 + n];
    } else if (i < OFF_WA1T) {
        int j = i - OFF_WZT; int n = j >> 9, k = j & 511;
        v = wz_w[k * 64 + n];
    } else if (i < OFF_WA2T) {
        int j = i - OFF_WA1T; int n = j >> 7, k = j & 127;
        v = wa1_w[k * 64 + n];
    } else {
        int j = i - OFF_WA2T; int n = j >> 6, k = j & 63;
        v = wa2_w[k * NF + n];
    }
    ws[i] = f2bf(v);
}

// ---------------- Kernel 1: shape functions (unchanged) ----------------
#define SROWS 64
__global__ __launch_bounds__(576) void shape_kernel(
    const float* __restrict__ q,
    const float* __restrict__ w1_1, const float* __restrict__ b1_1,
    const float* __restrict__ w2_1, const float* __restrict__ b2_1,
    const float* __restrict__ w3_1, const float* __restrict__ b3_1,
    const float* __restrict__ w1_2, const float* __restrict__ b1_2,
    const float* __restrict__ w2_2, const float* __restrict__ b2_2,
    const float* __restrict__ w3_2, const float* __restrict__ b3_2,
    float* __restrict__ shape_out, int B)
{
    __shared__ float qs[SROWS][NAG];

    int tid = threadIdx.x;
    int f = tid;
    bool valid = f < NF;
    int fe = valid ? f : (NF - 1);

    float w1a[8], w1b[8], b1v[8], w2v[32], b2v[4], w3v[4], b3v;
    int pi, pj;
    if (fe < N1C) {
        int n = fe;
        pi = n; pj = n;
        #pragma unroll
        for (int k = 0; k < 8; k++) { w1a[k] = fabsf(w1_1[n*8+k]); w1b[k] = 0.f; b1v[k] = b1_1[n*8+k]; }
        #pragma unroll
        for (int t = 0; t < 32; t++) w2v[t] = fabsf(w2_1[n*32+t]);
        #pragma unroll
        for (int j = 0; j < 4; j++) { b2v[j] = b2_1[n*4+j]; w3v[j] = fabsf(w3_1[n*4+j]); }
        b3v = b3_1[n];
    } else {
        int n = fe - N1C;
        int p = n, i = 0, c = NAG - 1;
        while (p >= c) { p -= c; c--; i++; }
        pi = i; pj = i + 1 + p;
        #pragma unroll
        for (int k = 0; k < 8; k++) { w1a[k] = fabsf(w1_2[n*16+k]); w1b[k] = fabsf(w1_2[n*16+8+k]); b1v[k] = b1_2[n*8+k]; }
        #pragma unroll
        for (int t = 0; t < 32; t++) w2v[t] = fabsf(w2_2[n*32+t]);
        #pragma unroll
        for (int j = 0; j < 4; j++) { b2v[j] = b2_2[n*4+j]; w3v[j] = fabsf(w3_2[n*4+j]); }
        b3v = b3_2[n];
    }

    int row0 = blockIdx.x * SROWS;
    if (tid < 512) {
        float4 v = *(const float4*)&q[(size_t)row0 * NAG + tid * 4];
        *(float4*)&((float*)qs)[tid * 4] = v;
    }
    __syncthreads();

    #pragma unroll 4
    for (int rr = 0; rr < SROWS; rr++) {
        float qi = qs[rr][pi];
        float qj = qs[rr][pj];
        float h1[8];
        #pragma unroll
        for (int k = 0; k < 8; k++) h1[k] = elu_f(w1a[k]*qi + w1b[k]*qj + b1v[k]);
        float h2[4];
        #pragma unroll
        for (int j = 0; j < 4; j++) {
            float a = b2v[j];
            #pragma unroll
            for (int k = 0; k < 8; k++) a += h1[k] * w2v[k*4 + j];
            h2[j] = elu_f(a);
        }
        float fv = b3v;
        #pragma unroll
        for (int j = 0; j < 4; j++) fv += h2[j] * w3v[j];
        if (valid) shape_out[(size_t)(row0 + rr) * NF + f] = fv;
    }
}

// ---------------- Kernel 2: zero-barrier big-burst MFMA encoder ----------------
// Evidence (R0/R2/R4): effective BW pinned ~1.37 TB/s regardless of occupancy or
// barrier structure -> loads-in-flight + DRAM burst size is the lever.
// Wave w owns rows [16w,16w+16) end-to-end (no redundant reads). A staged in
// K-halves of 256: 16 x 1KB CONTIGUOUS row-bursts issued per wave (vs 256B
// scattered chunks before), packed to bf16 into a WAVE-PRIVATE LDS region, then
// a 64-MFMA phase with the whole B-stream pipelining from L2 uninterrupted.
// Wave-private staging -> ZERO __syncthreads in the entire kernel.
// LDS 60.4KB -> 2 blocks/CU (grid-limited at 2 anyway).
#define RB 64
#define KH 256
#define SAP 264   // KH + 8 shorts pad: 16B-aligned rows, 2-way (free) bank alias

__global__ __launch_bounds__(256, 2) void enc_mfma(
    const float* __restrict__ state,
    const float* __restrict__ sem,
    const unsigned short* __restrict__ wsbuf,
    const float* __restrict__ ws_b, const float* __restrict__ wz_b,
    const float* __restrict__ wa1_b, const float* __restrict__ wa2_b,
    const float* __restrict__ wb1_b, const float* __restrict__ wb2_w,
    const float* __restrict__ wb2_b,
    const float* __restrict__ shape_out,
    float* __restrict__ q_total,
    float* __restrict__ attn_out)
{
    __shared__ unsigned short sA[RB][SAP];    // staged A half-tile (bf16)
    __shared__ unsigned short sComb[RB][136]; // [relu(C1)|relu(C3)], padded
    __shared__ unsigned short sH[RB][72];     // relu(C4), padded

    const unsigned short* wsT  = wsbuf + OFF_WST;
    const unsigned short* wb1T = wsbuf + OFF_WB1T;
    const unsigned short* wzT  = wsbuf + OFF_WZT;
    const unsigned short* wa1T = wsbuf + OFF_WA1T;
    const unsigned short* wa2T = wsbuf + OFF_WA2T;

    int tid  = threadIdx.x;
    int lane = tid & 63;
    int w    = tid >> 6;
    int col  = lane & 15;
    int quad = lane >> 4;
    int r0   = blockIdx.x * RB;
    int rowt = w * 16;

    const unsigned short* bS0 = wsT  + col * SD + quad * 8;
    const unsigned short* bB0 = wb1T + col * SD + quad * 8;
    const unsigned short* bZ0 = wzT  + col * SD + quad * 8;

    f32x4 accS[4], accB[4], accZ[4];
    #pragma unroll
    for (int ct = 0; ct < 4; ct++) {
        accS[ct] = (f32x4){0.f,0.f,0.f,0.f};
        accB[ct] = (f32x4){0.f,0.f,0.f,0.f};
        accZ[ct] = (f32x4){0.f,0.f,0.f,0.f};
    }

    // ---- state -> accS (ws), accB (wb1): two K-halves, wave-private staging ----
    #pragma unroll 1
    for (int h = 0; h < 2; h++) {
        int c0 = h * KH;
        // stage 16 own rows: 1KB contiguous burst per row, 8 rows in flight
        #pragma unroll
        for (int b = 0; b < 2; b++) {
            float4 v[8];
            #pragma unroll
            for (int i = 0; i < 8; i++)
                v[i] = *(const float4*)&state[(size_t)(r0 + rowt + b*8 + i) * SD + c0 + lane * 4];
            #pragma unroll
            for (int i = 0; i < 8; i++) {
                uint2 p; p.x = pack2(v[i].x, v[i].y); p.y = pack2(v[i].z, v[i].w);
                *(uint2*)&sA[rowt + b*8 + i][lane * 4] = p;
            }
        }
        // compute: 8 K-slices x 4 ct x 2 mats = 64 MFMAs, B-loads pipeline freely
        #pragma unroll
        for (int ks = 0; ks < 8; ks++) {
            bf16x8 a = *(const bf16x8*)&sA[rowt + col][ks * 32 + quad * 8];
            int wof = c0 + ks * 32;
            #pragma unroll
            for (int ct = 0; ct < 4; ct++) {
                bf16x8 bS = *(const bf16x8*)(bS0 + ct * 16 * SD + wof);
                bf16x8 bB = *(const bf16x8*)(bB0 + ct * 16 * SD + wof);
                accS[ct] = MFMA16(a, bS, accS[ct]);
                accB[ct] = MFMA16(a, bB, accB[ct]);
            }
        }
    }

    // ---- sem -> accZ (wz): same pattern ----
    #pragma unroll 1
    for (int h = 0; h < 2; h++) {
        int c0 = h * KH;
        #pragma unroll
        for (int b = 0; b < 2; b++) {
            float4 v[8];
            #pragma unroll
            for (int i = 0; i < 8; i++)
                v[i] = *(const float4*)&sem[(size_t)(r0 + rowt + b*8 + i) * SD + c0 + lane * 4];
            #pragma unroll
            for (int i = 0; i < 8; i++) {
                uint2 p; p.x = pack2(v[i].x, v[i].y); p.y = pack2(v[i].z, v[i].w);
                *(uint2*)&sA[rowt + b*8 + i][lane * 4] = p;
            }
        }
        #pragma unroll
        for (int ks = 0; ks < 8; ks++) {
            bf16x8 a = *(const bf16x8*)&sA[rowt + col][ks * 32 + quad * 8];
            int wof = c0 + ks * 32;
            #pragma unroll
            for (int ct = 0; ct < 4; ct++) {
                bf16x8 bZ = *(const bf16x8*)(bZ0 + ct * 16 * SD + wof);
                accZ[ct] = MFMA16(a, bZ, accZ[ct]);
            }
        }
    }

    // ---- comb = [relu(C1+ws_b) | relu(C3+wz_b)] (own rows only -> no barrier) ----
    #pragma unroll
    for (int ct = 0; ct < 4; ct++) {
        float bs = ws_b[ct * 16 + col];
        float bz = wz_b[ct * 16 + col];
        #pragma unroll
        for (int reg = 0; reg < 4; reg++) {
            int rr = rowt + quad * 4 + reg;
            sComb[rr][ct * 16 + col]      = f2bf(fmaxf(accS[ct][reg] + bs, 0.f));
            sComb[rr][64 + ct * 16 + col] = f2bf(fmaxf(accZ[ct][reg] + bz, 0.f));
        }
    }

    // ---- bias head: qb = relu(C2+wb1_b) @ wb2_w ----
    float qbv[4];
    #pragma unroll
    for (int reg = 0; reg < 4; reg++) {
        float p = 0.f;
        #pragma unroll
        for (int ct = 0; ct < 4; ct++)
            p += fmaxf(accB[ct][reg] + wb1_b[ct * 16 + col], 0.f) * wb2_w[ct * 16 + col];
        #pragma unroll
        for (int m = 1; m < 16; m <<= 1) p += __shfl_xor(p, m, 64);
        qbv[reg] = p;
    }

    // ---- C4 = comb @ wa1 (own rows) ----
    f32x4 accH[4];
    #pragma unroll
    for (int ct = 0; ct < 4; ct++) accH[ct] = (f32x4){0.f,0.f,0.f,0.f};
    #pragma unroll
    for (int ks = 0; ks < 4; ks++) {
        bf16x8 a = *(const bf16x8*)&sComb[rowt + col][ks * 32 + quad * 8];
        #pragma unroll
        for (int ct = 0; ct < 4; ct++) {
            bf16x8 b = *(const bf16x8*)&wa1T[(ct * 16 + col) * 128 + ks * 32 + quad * 8];
            accH[ct] = MFMA16(a, b, accH[ct]);
        }
    }
    #pragma unroll
    for (int ct = 0; ct < 4; ct++) {
        float bh = wa1_b[ct * 16 + col];
        #pragma unroll
        for (int reg = 0; reg < 4; reg++)
            sH[rowt + quad * 4 + reg][ct * 16 + col] = f2bf(fmaxf(accH[ct][reg] + bh, 0.f));
    }

    bf16x8 ha0 = *(const bf16x8*)&sH[rowt + col][quad * 8];
    bf16x8 ha1 = *(const bf16x8*)&sH[rowt + col][32 + quad * 8];

    // ---- pass 1: sum of exp(logits), weighted sum with shape_out ----
    float sAcc[4] = {0.f,0.f,0.f,0.f};
    float wAcc[4] = {0.f,0.f,0.f,0.f};
    for (int nt = 0; nt < 33; nt++) {
        f32x4 acc = (f32x4){0.f,0.f,0.f,0.f};
        const unsigned short* wp = &wa2T[(nt * 16 + col) * 64 + quad * 8];
        acc = MFMA16(ha0, *(const bf16x8*)wp, acc);
        acc = MFMA16(ha1, *(const bf16x8*)(wp + 32), acc);
        float lb = wa2_b[nt * 16 + col];
        #pragma unroll
        for (int reg = 0; reg < 4; reg++) {
            float e = __expf(acc[reg] + lb);
            sAcc[reg] += e;
            wAcc[reg] += e * shape_out[(size_t)(r0 + rowt + quad * 4 + reg) * NF + nt * 16 + col];
        }
    }
    float inv[4];
    #pragma unroll
    for (int reg = 0; reg < 4; reg++) {
        float s = sAcc[reg], ww = wAcc[reg];
        #pragma unroll
        for (int m = 1; m < 16; m <<= 1) { s += __shfl_xor(s, m, 64); ww += __shfl_xor(ww, m, 64); }
        inv[reg] = 1.f / s;
        if (col == 0)
            q_total[r0 + rowt + quad * 4 + reg] = ww * inv[reg] + qbv[reg] + wb2_b[0];
    }

    // ---- pass 2: write normalized attention ----
    for (int nt = 0; nt < 33; nt++) {
        f32x4 acc = (f32x4){0.f,0.f,0.f,0.f};
        const unsigned short* wp = &wa2T[(nt * 16 + col) * 64 + quad * 8];
        acc = MFMA16(ha0, *(const bf16x8*)wp, acc);
        acc = MFMA16(ha1, *(const bf16x8*)(wp + 32), acc);
        float lb = wa2_b[nt * 16 + col];
        #pragma unroll
        for (int reg = 0; reg < 4; reg++) {
            float e = __expf(acc[reg] + lb);
            attn_out[(size_t)(r0 + rowt + quad * 4 + reg) * NF + nt * 16 + col] = e * inv[reg];
        }
    }
}

extern "C" void kernel_launch(void* const* d_in, const int* in_sizes, int n_in,
                              void* d_out, int out_size, void* d_ws, size_t ws_size,
                              hipStream_t stream) {
    const float* q     = (const float*)d_in[0];
    const float* state = (const float*)d_in[1];
    const float* sem   = (const float*)d_in[2];
    const float* w1_1  = (const float*)d_in[3];
    const float* b1_1  = (const float*)d_in[4];
    const float* w2_1  = (const float*)d_in[5];
    const float* b2_1  = (const float*)d_in[6];
    const float* w3_1  = (const float*)d_in[7];
    const float* b3_1  = (const float*)d_in[8];
    const float* w1_2  = (const float*)d_in[9];
    const float* b1_2  = (const float*)d_in[10];
    const float* w2_2  = (const float*)d_in[11];
    const float* b2_2  = (const float*)d_in[12];
    const float* w3_2  = (const float*)d_in[13];
    const float* b3_2  = (const float*)d_in[14];
    const float* ws_w  = (const float*)d_in[15];
    const float* ws_b  = (const float*)d_in[16];
    const float* wz_w  = (const float*)d_in[17];
    const float* wz_b  = (const float*)d_in[18];
    const float* wa1_w = (const float*)d_in[19];
    const float* wa1_b = (const float*)d_in[20];
    const float* wa2_w = (const float*)d_in[21];
    const float* wa2_b = (const float*)d_in[22];
    const float* wb1_w = (const float*)d_in[23];
    const float* wb1_b = (const float*)d_in[24];
    const float* wb2_w = (const float*)d_in[25];
    const float* wb2_b = (const float*)d_in[26];

    int B = in_sizes[0] / NAG;

    float* out_q    = (float*)d_out;                 // [B]
    float* out_attn = out_q + B;                     // [B, NF]
    float* out_shp  = out_attn + (size_t)B * NF;     // [B, NF]

    unsigned short* wsbuf = (unsigned short*)d_ws;

    prep_kernel<<<(PREP_TOT + 255) / 256, 256, 0, stream>>>(
        ws_w, wb1_w, wz_w, wa1_w, wa2_w, wsbuf);

    shape_kernel<<<B / SROWS, 576, 0, stream>>>(q,
        w1_1, b1_1, w2_1, b2_1, w3_1, b3_1,
        w1_2, b1_2, w2_2, b2_2, w3_2, b3_2,
        out_shp, B);

    enc_mfma<<<B / RB, 256, 0, stream>>>(state, sem, wsbuf,
        ws_b, wz_b, wa1_b, wa2_b, wb1_b, wb2_w, wb2_b,
        out_shp, out_q, out_attn);
}